// Round 6
// baseline (193.060 us; speedup 1.0000x reference)
//
#include <hip/hip_runtime.h>
#include <math.h>

#define T_TOK 1024
#define H_DIM 1024
#define NEXP  16
#define I_DIM 512
#define ISH   1024
#define GU_GRID 640
#define DN_GRID 512

typedef __bf16 bf16;
typedef __bf16 bf16x4 __attribute__((ext_vector_type(4)));
typedef __bf16 bf16x8 __attribute__((ext_vector_type(8)));
typedef float  f32x4  __attribute__((ext_vector_type(4)));

#define MFMA(a,b,c) __builtin_amdgcn_mfma_f32_16x16x32_bf16(a,b,c,0,0,0)

__device__ __forceinline__ bf16x8 cvt8(float4 a, float4 b) {
    return (bf16x8){ (bf16)a.x,(bf16)a.y,(bf16)a.z,(bf16)a.w,
                     (bf16)b.x,(bf16)b.y,(bf16)b.z,(bf16)b.w };
}

// ---------------- fused cast(x->bf16) + router: 4 tokens/block, 1 wave/token ----------------
__global__ __launch_bounds__(256) void k_cast_router(const float* __restrict__ x,
        const float* __restrict__ gw, const float* __restrict__ bias,
        bf16* __restrict__ xb, int* __restrict__ tok_e, float* __restrict__ tok_w)
{
    int t = blockIdx.x * 4 + (threadIdx.x >> 6);
    int lane = threadIdx.x & 63;
    const float* xrow = x + (size_t)t * H_DIM + lane * 16;
    bf16* xbrow = xb + (size_t)t * H_DIM + lane * 16;
    float acc[NEXP];
    #pragma unroll
    for (int e = 0; e < NEXP; ++e) acc[e] = 0.f;
    #pragma unroll
    for (int kc = 0; kc < 4; ++kc) {
        float4 xv = *(const float4*)(xrow + kc * 4);
        bf16x4 o = { (bf16)xv.x, (bf16)xv.y, (bf16)xv.z, (bf16)xv.w };
        *(bf16x4*)(xbrow + kc * 4) = o;
        const float* gp = gw + lane * 16 + kc * 4;
        #pragma unroll
        for (int e = 0; e < NEXP; ++e) {
            float4 wv = *(const float4*)(gp + e * H_DIM);
            acc[e] += xv.x * wv.x + xv.y * wv.y + xv.z * wv.z + xv.w * wv.w;
        }
    }
    #pragma unroll
    for (int e = 0; e < NEXP; ++e) {
        float v = acc[e];
        #pragma unroll
        for (int off = 1; off < 64; off <<= 1) v += __shfl_xor(v, off);
        acc[e] = v;
    }
    if (lane == 0) {
        float sc[NEXP], bi[NEXP];
        #pragma unroll
        for (int e = 0; e < NEXP; ++e) {
            sc[e] = 1.f / (1.f + expf(-acc[e]));
            bi[e] = sc[e] + bias[e];
        }
        int i1 = 0; float b1 = bi[0];
        for (int e = 1; e < NEXP; ++e) if (bi[e] > b1) { b1 = bi[e]; i1 = e; }
        int i2 = -1; float b2 = -1e30f;
        for (int e = 0; e < NEXP; ++e) { if (e == i1) continue; if (bi[e] > b2) { b2 = bi[e]; i2 = e; } }
        float w1 = sc[i1], w2 = sc[i2];
        float s = w1 + w2;
        w1 /= s; w2 /= s;
        tok_e[t * 2]     = i1;  tok_e[t * 2 + 1] = i2;
        tok_w[t * 2]     = w1;  tok_w[t * 2 + 1] = w2;
    }
}

// ---------------- build: histogram + scan + scatter + WAVE-granular worklists ----------------
// gu wave: 64 rows x (16 gate + 16 up cols).  dn wave: 64 rows x 32 cols.
// entry: routed (e<<16)|(mt<<8)|nx ; shared (1<<30)|(mt<<8)|nx
__global__ __launch_bounds__(256) void k_build(const int* __restrict__ tok_e,
        const float* __restrict__ tok_w, int* __restrict__ offs_g,
        int* __restrict__ row_token, float* __restrict__ row_w,
        int* __restrict__ wl_gu, int* __restrict__ n_gu,
        int* __restrict__ wl_dn, int* __restrict__ n_dn)
{
    __shared__ int cnt[NEXP], cur[NEXP], tcnt[NEXP], toff[NEXP + 1];
    int tid = threadIdx.x;
    if (tid < NEXP) cnt[tid] = 0;
    __syncthreads();
    for (int p = tid; p < 2 * T_TOK; p += 256) atomicAdd(&cnt[tok_e[p]], 1);
    __syncthreads();
    if (tid == 0) {
        int s = 0, ts = 0;
        for (int e = 0; e < NEXP; ++e) {
            offs_g[e] = s; cur[e] = s;
            tcnt[e] = (cnt[e] + 63) >> 6;
            toff[e] = ts; ts += tcnt[e]; s += cnt[e];
        }
        offs_g[NEXP] = s; toff[NEXP] = ts;
        *n_gu = ts * 32 + 1024;   // routed: tcnt*32 ntiles ; shared: 16 mt * 64 nx
        *n_dn = ts * 32 + 512;    // routed: tcnt*32 ; shared: 16 mt * 32 nx
    }
    __syncthreads();
    for (int p = tid; p < 2 * T_TOK; p += 256) {
        int e = tok_e[p];
        int pos = atomicAdd(&cur[e], 1);
        row_token[pos] = p >> 1;
        row_w[pos] = tok_w[p];
    }
    int ntr = toff[NEXP];
    int tot_gu = ntr * 32 + 1024;
    for (int idx = tid; idx < tot_gu; idx += 256) {
        int entry;
        if (idx < ntr * 32) {
            int t32 = idx >> 5;
            int e = 0;
            while (!(t32 >= toff[e] && t32 < toff[e + 1])) ++e;
            int j = idx - toff[e] * 32;
            int nx = j / tcnt[e], mt = j % tcnt[e];
            entry = (e << 16) | (mt << 8) | nx;
        } else {
            int j = idx - ntr * 32;
            int nx = j >> 4, mt = j & 15;
            entry = (1 << 30) | (mt << 8) | nx;
        }
        wl_gu[idx] = entry;
    }
    int tot_dn = ntr * 32 + 512;
    for (int idx = tid; idx < tot_dn; idx += 256) {
        int entry;
        if (idx < ntr * 32) {
            int t32 = idx >> 5;
            int e = 0;
            while (!(t32 >= toff[e] && t32 < toff[e + 1])) ++e;
            int j = idx - toff[e] * 32;
            int nx = j / tcnt[e], mt = j % tcnt[e];
            entry = (e << 16) | (mt << 8) | nx;
        } else {
            int j = idx - ntr * 32;
            int nx = j >> 4, mt = j & 15;
            entry = (1 << 30) | (mt << 8) | nx;
        }
        wl_dn[idx] = entry;
    }
}

// ---------------- gate_up + SwiGLU: barrier-free, direct-fragment, per-wave 64x(16+16) ----------------
__global__ __launch_bounds__(256) void k_gu_all(
    const bf16* __restrict__ xb, const float* __restrict__ wgu, const float* __restrict__ sgu,
    bf16* __restrict__ act, bf16* __restrict__ act2,
    const int* __restrict__ offs, const int* __restrict__ row_token,
    const int* __restrict__ wl, const int* __restrict__ n_wl)
{
    int w = threadIdx.x >> 6, lane = threadIdx.x & 63;
    int bid = blockIdx.x;
    int idx = ((bid & 7) * (GU_GRID >> 3) + (bid >> 3)) * 4 + w;   // XCD-chunk swizzle
    if (idx >= *n_wl) return;
    int entry = wl[idx];
    bool sh = entry & (1 << 30);
    int mt = (entry >> 8) & 255, nx = entry & 255;
    int lr = lane & 15, lk8 = (lane >> 4) * 8;
    int n0 = nx * 16;

    int m0, mcnt, ldo;
    const float* W;
    bf16* dst;
    const bf16* pA[4];
    if (sh) {
        m0 = mt * 64; mcnt = 64; W = sgu; ldo = ISH; dst = act2;
        #pragma unroll
        for (int mf = 0; mf < 4; ++mf)
            pA[mf] = xb + (size_t)(m0 + mf * 16 + lr) * H_DIM + lk8;
    } else {
        int e = (entry >> 16) & 15;
        m0 = offs[e] + mt * 64; mcnt = min(64, offs[e + 1] - m0);
        W = wgu + (size_t)e * (2 * (size_t)I_DIM * H_DIM); ldo = I_DIM; dst = act;
        #pragma unroll
        for (int mf = 0; mf < 4; ++mf) {
            int r = min(m0 + mf * 16 + lr, m0 + mcnt - 1);
            pA[mf] = xb + (size_t)row_token[r] * H_DIM + lk8;
        }
    }
    const float* pG = W + (size_t)(n0 + lr) * H_DIM + lk8;
    const float* pU = W + (size_t)(ldo + n0 + lr) * H_DIM + lk8;

    f32x4 aG[4], aU[4];
    #pragma unroll
    for (int mf = 0; mf < 4; ++mf) { aG[mf] = (f32x4){0,0,0,0}; aU[mf] = (f32x4){0,0,0,0}; }

    bf16x8 rA0[4], rA1[4];
    float4 rG0[2], rG1[2], rU0[2], rU1[2];

#define GU_LD(RA,RG,RU,K) { \
    _Pragma("unroll") \
    for (int mf = 0; mf < 4; ++mf) RA[mf] = *(const bf16x8*)(pA[mf] + (K)); \
    RG[0] = *(const float4*)(pG + (K)); RG[1] = *(const float4*)(pG + (K) + 4); \
    RU[0] = *(const float4*)(pU + (K)); RU[1] = *(const float4*)(pU + (K) + 4); }
#define GU_ST(RA,RG,RU) { \
    bf16x8 bg = cvt8(RG[0], RG[1]), bu = cvt8(RU[0], RU[1]); \
    _Pragma("unroll") \
    for (int mf = 0; mf < 4; ++mf) { aG[mf] = MFMA(RA[mf], bg, aG[mf]); aU[mf] = MFMA(RA[mf], bu, aU[mf]); } }

    GU_LD(rA0, rG0, rU0, 0)
    for (int k0 = 0; k0 < H_DIM; k0 += 64) {
        GU_LD(rA1, rG1, rU1, k0 + 32)
        GU_ST(rA0, rG0, rU0)
        if (k0 + 64 < H_DIM) GU_LD(rA0, rG0, rU0, k0 + 64)
        GU_ST(rA1, rG1, rU1)
    }
#undef GU_LD
#undef GU_ST

    #pragma unroll
    for (int mf = 0; mf < 4; ++mf) {
        #pragma unroll
        for (int j = 0; j < 4; ++j) {
            int rl = mf * 16 + (lane >> 4) * 4 + j;
            if (rl < mcnt) {
                float g = aG[mf][j], u = aU[mf][j];
                float v = (g / (1.f + __expf(-g))) * u;
                dst[(size_t)(m0 + rl) * ldo + n0 + lr] = (bf16)v;
            }
        }
    }
}

// ---------------- down proj: barrier-free, direct-fragment, per-wave 64x32 ----------------
__global__ __launch_bounds__(256) void k_dn_all(
    const bf16* __restrict__ act, const bf16* __restrict__ act2,
    const float* __restrict__ wd, const float* __restrict__ sd, float* __restrict__ out,
    const int* __restrict__ offs, const int* __restrict__ row_token, const float* __restrict__ row_w,
    const int* __restrict__ wl, const int* __restrict__ n_wl)
{
    int w = threadIdx.x >> 6, lane = threadIdx.x & 63;
    int bid = blockIdx.x;
    int idx = ((bid & 7) * (DN_GRID >> 3) + (bid >> 3)) * 4 + w;
    if (idx >= *n_wl) return;
    int entry = wl[idx];
    bool sh = entry & (1 << 30);
    int mt = (entry >> 8) & 255, nx = entry & 255;
    int lr = lane & 15, lk8 = (lane >> 4) * 8;
    int n0 = nx * 32;

    int m0, mcnt, K;
    const bf16* A;
    const float* W;
    if (sh) { m0 = mt * 64; mcnt = 64; A = act2; W = sd; K = ISH; }
    else {
        int e = (entry >> 16) & 15;
        m0 = offs[e] + mt * 64; mcnt = min(64, offs[e + 1] - m0);
        A = act; W = wd + (size_t)e * H_DIM * I_DIM; K = I_DIM;
    }
    const bf16* pA[4];
    #pragma unroll
    for (int mf = 0; mf < 4; ++mf) {
        int r = min(m0 + mf * 16 + lr, m0 + mcnt - 1);
        pA[mf] = A + (size_t)r * K + lk8;
    }
    const float* pB0 = W + (size_t)(n0 + lr) * K + lk8;
    const float* pB1 = W + (size_t)(n0 + 16 + lr) * K + lk8;

    f32x4 acc[4][2];
    #pragma unroll
    for (int mf = 0; mf < 4; ++mf) { acc[mf][0] = (f32x4){0,0,0,0}; acc[mf][1] = (f32x4){0,0,0,0}; }

    bf16x8 rA0[4], rA1[4];
    float4 rB0[4], rB1[4];

#define DN_LD(RA,RB,K0) { \
    _Pragma("unroll") \
    for (int mf = 0; mf < 4; ++mf) RA[mf] = *(const bf16x8*)(pA[mf] + (K0)); \
    RB[0] = *(const float4*)(pB0 + (K0)); RB[1] = *(const float4*)(pB0 + (K0) + 4); \
    RB[2] = *(const float4*)(pB1 + (K0)); RB[3] = *(const float4*)(pB1 + (K0) + 4); }
#define DN_ST(RA,RB) { \
    bf16x8 b0 = cvt8(RB[0], RB[1]), b1 = cvt8(RB[2], RB[3]); \
    _Pragma("unroll") \
    for (int mf = 0; mf < 4; ++mf) { acc[mf][0] = MFMA(RA[mf], b0, acc[mf][0]); acc[mf][1] = MFMA(RA[mf], b1, acc[mf][1]); } }

    DN_LD(rA0, rB0, 0)
    for (int k0 = 0; k0 < K; k0 += 64) {
        DN_LD(rA1, rB1, k0 + 32)
        DN_ST(rA0, rB0)
        if (k0 + 64 < K) DN_LD(rA0, rB0, k0 + 64)
        DN_ST(rA1, rB1)
    }
#undef DN_LD
#undef DN_ST

    #pragma unroll
    for (int mf = 0; mf < 4; ++mf) {
        #pragma unroll
        for (int j = 0; j < 4; ++j) {
            int rl = mf * 16 + (lane >> 4) * 4 + j;
            if (rl < mcnt) {
                if (sh) {
                    atomicAdd(&out[(size_t)(m0 + rl) * H_DIM + n0 + lr],      acc[mf][0][j]);
                    atomicAdd(&out[(size_t)(m0 + rl) * H_DIM + n0 + 16 + lr], acc[mf][1][j]);
                } else {
                    int t = row_token[m0 + rl];
                    float wt = row_w[m0 + rl];
                    atomicAdd(&out[(size_t)t * H_DIM + n0 + lr],      wt * acc[mf][0][j]);
                    atomicAdd(&out[(size_t)t * H_DIM + n0 + 16 + lr], wt * acc[mf][1][j]);
                }
            }
        }
    }
}

extern "C" void kernel_launch(void* const* d_in, const int* in_sizes, int n_in,
                              void* d_out, int out_size, void* d_ws, size_t ws_size,
                              hipStream_t stream)
{
    (void)in_sizes; (void)n_in; (void)out_size; (void)ws_size;
    const float* x    = (const float*)d_in[0];
    const float* gw   = (const float*)d_in[1];
    const float* bias = (const float*)d_in[2];
    const float* wgu  = (const float*)d_in[3];
    const float* wd   = (const float*)d_in[4];
    const float* sgu  = (const float*)d_in[5];
    const float* sd   = (const float*)d_in[6];
    float* out = (float*)d_out;

    char* ws = (char*)d_ws;
    int*   offs_g    = (int*)(ws);            // 17 ints
    int*   n_gu      = (int*)(ws + 128);
    int*   n_dn      = (int*)(ws + 132);
    int*   wl_gu     = (int*)(ws + 256);      // up to 2560 ints
    int*   wl_dn     = (int*)(ws + 12288);    // up to 2048 ints
    int*   tok_e     = (int*)(ws + 24576);
    float* tok_w     = (float*)(ws + 32768);
    int*   row_token = (int*)(ws + 40960);
    float* row_w     = (float*)(ws + 49152);
    bf16*  xb        = (bf16*)(ws + 65536);
    bf16*  act       = (bf16*)(ws + 65536 + (1 << 21));
    bf16*  act2      = (bf16*)(ws + 65536 + (2 << 21));

    hipMemsetAsync(out, 0, (size_t)T_TOK * H_DIM * sizeof(float), stream);
    k_cast_router<<<T_TOK / 4, 256, 0, stream>>>(x, gw, bias, xb, tok_e, tok_w);
    k_build<<<1, 256, 0, stream>>>(tok_e, tok_w, offs_g, row_token, row_w,
                                   wl_gu, n_gu, wl_dn, n_dn);
    k_gu_all<<<GU_GRID, 256, 0, stream>>>(xb, wgu, sgu, act, act2,
                                          offs_g, row_token, wl_gu, n_gu);
    k_dn_all<<<DN_GRID, 256, 0, stream>>>(act, act2, wd, sd, out,
                                          offs_g, row_token, row_w, wl_dn, n_dn);
}

// Round 7
// 115.156 us; speedup vs baseline: 1.6765x; 1.6765x over previous
//
#include <hip/hip_runtime.h>
#include <math.h>

#define T_TOK 1024
#define H_DIM 1024
#define NEXP  16
#define I_DIM 512
#define ISH   1024
#define GU_GRID 2304
#define DN_GRID 1792

typedef __bf16 bf16;
typedef __bf16 bf16x4 __attribute__((ext_vector_type(4)));
typedef __bf16 bf16x8 __attribute__((ext_vector_type(8)));
typedef float  f32x4  __attribute__((ext_vector_type(4)));

#define MFMA(a,b,c) __builtin_amdgcn_mfma_f32_16x16x32_bf16(a,b,c,0,0,0)

__device__ __forceinline__ bf16x8 cvt8(float4 a, float4 b) {
    return (bf16x8){ (bf16)a.x,(bf16)a.y,(bf16)a.z,(bf16)a.w,
                     (bf16)b.x,(bf16)b.y,(bf16)b.z,(bf16)b.w };
}

// ---------------- fused cast(x->bf16) + router: 4 tokens/block, 1 wave/token ----------------
__global__ __launch_bounds__(256) void k_cast_router(const float* __restrict__ x,
        const float* __restrict__ gw, const float* __restrict__ bias,
        bf16* __restrict__ xb, int* __restrict__ tok_e, float* __restrict__ tok_w)
{
    int t = blockIdx.x * 4 + (threadIdx.x >> 6);
    int lane = threadIdx.x & 63;
    const float* xrow = x + (size_t)t * H_DIM + lane * 16;
    bf16* xbrow = xb + (size_t)t * H_DIM + lane * 16;
    float acc[NEXP];
    #pragma unroll
    for (int e = 0; e < NEXP; ++e) acc[e] = 0.f;
    #pragma unroll
    for (int kc = 0; kc < 4; ++kc) {
        float4 xv = *(const float4*)(xrow + kc * 4);
        bf16x4 o = { (bf16)xv.x, (bf16)xv.y, (bf16)xv.z, (bf16)xv.w };
        *(bf16x4*)(xbrow + kc * 4) = o;
        const float* gp = gw + lane * 16 + kc * 4;
        #pragma unroll
        for (int e = 0; e < NEXP; ++e) {
            float4 wv = *(const float4*)(gp + e * H_DIM);
            acc[e] += xv.x * wv.x + xv.y * wv.y + xv.z * wv.z + xv.w * wv.w;
        }
    }
    #pragma unroll
    for (int e = 0; e < NEXP; ++e) {
        float v = acc[e];
        #pragma unroll
        for (int off = 1; off < 64; off <<= 1) v += __shfl_xor(v, off);
        acc[e] = v;
    }
    if (lane == 0) {
        float sc[NEXP], bi[NEXP];
        #pragma unroll
        for (int e = 0; e < NEXP; ++e) {
            sc[e] = 1.f / (1.f + expf(-acc[e]));
            bi[e] = sc[e] + bias[e];
        }
        int i1 = 0; float b1 = bi[0];
        for (int e = 1; e < NEXP; ++e) if (bi[e] > b1) { b1 = bi[e]; i1 = e; }
        int i2 = -1; float b2 = -1e30f;
        for (int e = 0; e < NEXP; ++e) { if (e == i1) continue; if (bi[e] > b2) { b2 = bi[e]; i2 = e; } }
        float w1 = sc[i1], w2 = sc[i2];
        float s = w1 + w2;
        w1 /= s; w2 /= s;
        tok_e[t * 2]     = i1;  tok_e[t * 2 + 1] = i2;
        tok_w[t * 2]     = w1;  tok_w[t * 2 + 1] = w2;
    }
}

// ---------------- build: histogram + scan + scatter + BM=32 worklists ----------------
// entry: routed (e<<16)|(mt<<8)|nx ; shared (1<<30)|(mt<<8)|nx
__global__ __launch_bounds__(256) void k_build(const int* __restrict__ tok_e,
        const float* __restrict__ tok_w, int* __restrict__ offs_g,
        int* __restrict__ row_token, float* __restrict__ row_w,
        int* __restrict__ wl_gu, int* __restrict__ n_gu,
        int* __restrict__ wl_dn, int* __restrict__ n_dn)
{
    __shared__ int cnt[NEXP], cur[NEXP], tcnt[NEXP], toff[NEXP + 1];
    int tid = threadIdx.x;
    if (tid < NEXP) cnt[tid] = 0;
    __syncthreads();
    for (int p = tid; p < 2 * T_TOK; p += 256) atomicAdd(&cnt[tok_e[p]], 1);
    __syncthreads();
    if (tid == 0) {
        int s = 0, ts = 0;
        for (int e = 0; e < NEXP; ++e) {
            offs_g[e] = s; cur[e] = s;
            tcnt[e] = (cnt[e] + 31) >> 5;           // BM=32 tiles
            toff[e] = ts; ts += tcnt[e]; s += cnt[e];
        }
        offs_g[NEXP] = s; toff[NEXP] = ts;
        *n_gu = ts * 16 + 1024;    // routed: 16 nx ; shared: 32 mt * 32 nx
        *n_dn = ts * 16 + 512;     // routed: 16 nx ; shared: 32 mt * 16 nx
    }
    __syncthreads();
    for (int p = tid; p < 2 * T_TOK; p += 256) {
        int e = tok_e[p];
        int pos = atomicAdd(&cur[e], 1);
        row_token[pos] = p >> 1;
        row_w[pos] = tok_w[p];
    }
    int ntr = toff[NEXP];
    int tot_gu = ntr * 16 + 1024;
    for (int idx = tid; idx < tot_gu; idx += 256) {
        int entry;
        if (idx < ntr * 16) {
            int t16 = idx >> 4;
            int e = 0;
            while (!(t16 >= toff[e] && t16 < toff[e + 1])) ++e;
            int j = idx - toff[e] * 16;
            int nx = j / tcnt[e], mt = j % tcnt[e];   // nx outer, mt inner
            entry = (e << 16) | (mt << 8) | nx;
        } else {
            int j = idx - ntr * 16;
            int nx = j >> 5, mt = j & 31;
            entry = (1 << 30) | (mt << 8) | nx;
        }
        wl_gu[idx] = entry;
    }
    int tot_dn = ntr * 16 + 512;
    for (int idx = tid; idx < tot_dn; idx += 256) {
        int entry;
        if (idx < ntr * 16) {
            int t16 = idx >> 4;
            int e = 0;
            while (!(t16 >= toff[e] && t16 < toff[e + 1])) ++e;
            int j = idx - toff[e] * 16;
            int nx = j / tcnt[e], mt = j % tcnt[e];
            entry = (e << 16) | (mt << 8) | nx;
        } else {
            int j = idx - ntr * 16;
            int nx = j >> 5, mt = j & 31;
            entry = (1 << 30) | (mt << 8) | nx;
        }
        wl_dn[idx] = entry;
    }
}

// ---------------- gate_up + SwiGLU: BM=32, 32 gate + 32 up cols, BK=64 ----------------
__global__ __launch_bounds__(256) void k_gu_all(
    const bf16* __restrict__ xb, const float* __restrict__ wgu, const float* __restrict__ sgu,
    bf16* __restrict__ act, bf16* __restrict__ act2,
    const int* __restrict__ offs, const int* __restrict__ row_token,
    const int* __restrict__ wl, const int* __restrict__ n_wl)
{
    int bid = blockIdx.x;
    int idx = (bid & 7) * (GU_GRID >> 3) + (bid >> 3);   // XCD-chunk swizzle
    if (idx >= *n_wl) return;
    int entry = wl[idx];
    bool sh = entry & (1 << 30);
    int mt = (entry >> 8) & 255, nx = entry & 255;
    int m0, mcnt, ldo;
    const float* W;
    bf16* dst;
    if (sh) { m0 = mt * 32; mcnt = 32; W = sgu; ldo = ISH; dst = act2; }
    else {
        int e = (entry >> 16) & 15;
        m0 = offs[e] + mt * 32; mcnt = min(32, offs[e + 1] - m0);
        W = wgu + (size_t)e * (2 * (size_t)I_DIM * H_DIM); ldo = I_DIM; dst = act;
    }
    int n0 = nx * 32;

    __shared__ bf16 As[32][72];
    __shared__ bf16 Bg[32][72];
    __shared__ bf16 Bu[32][72];
    __shared__ int  toks[32];

    int tid = threadIdx.x;
    if (!sh) {
        if (tid < 32) toks[tid] = row_token[m0 + min(tid, mcnt - 1)];
        __syncthreads();
    }

    int r = tid >> 3, c8 = (tid & 7) * 8;
    int arow;
    if (sh) arow = m0 + r; else arow = toks[r];
    const bf16* a_src = xb + (size_t)arow * H_DIM + c8;
    const float* g_src = W + (size_t)(n0 + r) * H_DIM + c8;
    const float* u_src = W + (size_t)(ldo + n0 + r) * H_DIM + c8;

    int lane = tid & 63, w = tid >> 6, wm = w >> 1, wn = w & 1;
    int lr = lane & 15, lk8 = (lane >> 4) * 8;

    f32x4 aG = {0,0,0,0}, aU = {0,0,0,0};

    for (int k0 = 0; k0 < H_DIM; k0 += 64) {
        bf16x8 a8 = *(const bf16x8*)(a_src + k0);
        float4 g0 = *(const float4*)(g_src + k0), g1 = *(const float4*)(g_src + k0 + 4);
        float4 u0 = *(const float4*)(u_src + k0), u1 = *(const float4*)(u_src + k0 + 4);
        *(bf16x8*)&As[r][c8] = a8;
        *(bf16x8*)&Bg[r][c8] = cvt8(g0, g1);
        *(bf16x8*)&Bu[r][c8] = cvt8(u0, u1);
        __syncthreads();
        #pragma unroll
        for (int ks = 0; ks < 2; ++ks) {
            bf16x8 fa = *(const bf16x8*)&As[wm * 16 + lr][ks * 32 + lk8];
            bf16x8 fg = *(const bf16x8*)&Bg[wn * 16 + lr][ks * 32 + lk8];
            bf16x8 fu = *(const bf16x8*)&Bu[wn * 16 + lr][ks * 32 + lk8];
            aG = MFMA(fa, fg, aG);
            aU = MFMA(fa, fu, aU);
        }
        __syncthreads();
    }

    #pragma unroll
    for (int j = 0; j < 4; ++j) {
        int rl = wm * 16 + (lane >> 4) * 4 + j;
        if (rl < mcnt) {
            float g = aG[j], u = aU[j];
            float v = (g / (1.f + __expf(-g))) * u;
            dst[(size_t)(m0 + rl) * ldo + n0 + wn * 16 + lr] = (bf16)v;
        }
    }
}

// ---------------- down proj: BM=32, BN=64, BK=64 ----------------
__global__ __launch_bounds__(256) void k_dn_all(
    const bf16* __restrict__ act, const bf16* __restrict__ act2,
    const float* __restrict__ wd, const float* __restrict__ sd, float* __restrict__ out,
    const int* __restrict__ offs, const int* __restrict__ row_token, const float* __restrict__ row_w,
    const int* __restrict__ wl, const int* __restrict__ n_wl)
{
    int bid = blockIdx.x;
    int idx = (bid & 7) * (DN_GRID >> 3) + (bid >> 3);
    if (idx >= *n_wl) return;
    int entry = wl[idx];
    bool sh = entry & (1 << 30);
    int mt = (entry >> 8) & 255, nx = entry & 255;
    int m0, mcnt, K;
    const bf16* A;
    const float* W;
    if (sh) { m0 = mt * 32; mcnt = 32; A = act2; W = sd; K = ISH; }
    else {
        int e = (entry >> 16) & 15;
        m0 = offs[e] + mt * 32; mcnt = min(32, offs[e + 1] - m0);
        A = act; W = wd + (size_t)e * H_DIM * I_DIM; K = I_DIM;
    }
    int n0 = nx * 64;

    __shared__ bf16 As[32][72];
    __shared__ bf16 Bs[64][72];

    int tid = threadIdx.x;
    int ra = tid >> 3, ca8 = (tid & 7) * 8;
    int arow = m0 + (sh ? ra : min(ra, mcnt - 1));
    const bf16* a_src = A + (size_t)arow * K + ca8;
    int rb = tid >> 2, cb16 = (tid & 3) * 16;
    const float* b_src = W + (size_t)(n0 + rb) * K + cb16;

    int lane = tid & 63, w = tid >> 6, wm = w >> 1, wn = w & 1;
    int lr = lane & 15, lk8 = (lane >> 4) * 8;

    f32x4 acc[2] = {{0,0,0,0},{0,0,0,0}};

    for (int k0 = 0; k0 < K; k0 += 64) {
        bf16x8 a8 = *(const bf16x8*)(a_src + k0);
        float4 b0 = *(const float4*)(b_src + k0),     b1 = *(const float4*)(b_src + k0 + 4);
        float4 b2 = *(const float4*)(b_src + k0 + 8), b3 = *(const float4*)(b_src + k0 + 12);
        *(bf16x8*)&As[ra][ca8] = a8;
        *(bf16x8*)&Bs[rb][cb16]     = cvt8(b0, b1);
        *(bf16x8*)&Bs[rb][cb16 + 8] = cvt8(b2, b3);
        __syncthreads();
        #pragma unroll
        for (int ks = 0; ks < 2; ++ks) {
            bf16x8 fa  = *(const bf16x8*)&As[wm * 16 + lr][ks * 32 + lk8];
            bf16x8 fb0 = *(const bf16x8*)&Bs[wn * 32 + lr][ks * 32 + lk8];
            bf16x8 fb1 = *(const bf16x8*)&Bs[wn * 32 + 16 + lr][ks * 32 + lk8];
            acc[0] = MFMA(fa, fb0, acc[0]);
            acc[1] = MFMA(fa, fb1, acc[1]);
        }
        __syncthreads();
    }

    #pragma unroll
    for (int j = 0; j < 4; ++j) {
        int rl = wm * 16 + (lane >> 4) * 4 + j;
        if (rl < mcnt) {
            if (sh) {
                atomicAdd(&out[(size_t)(m0 + rl) * H_DIM + n0 + wn * 32 + lr],      acc[0][j]);
                atomicAdd(&out[(size_t)(m0 + rl) * H_DIM + n0 + wn * 32 + 16 + lr], acc[1][j]);
            } else {
                int t = row_token[m0 + rl];
                float wt = row_w[m0 + rl];
                atomicAdd(&out[(size_t)t * H_DIM + n0 + wn * 32 + lr],      wt * acc[0][j]);
                atomicAdd(&out[(size_t)t * H_DIM + n0 + wn * 32 + 16 + lr], wt * acc[1][j]);
            }
        }
    }
}

extern "C" void kernel_launch(void* const* d_in, const int* in_sizes, int n_in,
                              void* d_out, int out_size, void* d_ws, size_t ws_size,
                              hipStream_t stream)
{
    (void)in_sizes; (void)n_in; (void)out_size; (void)ws_size;
    const float* x    = (const float*)d_in[0];
    const float* gw   = (const float*)d_in[1];
    const float* bias = (const float*)d_in[2];
    const float* wgu  = (const float*)d_in[3];
    const float* wd   = (const float*)d_in[4];
    const float* sgu  = (const float*)d_in[5];
    const float* sd   = (const float*)d_in[6];
    float* out = (float*)d_out;

    char* ws = (char*)d_ws;
    int*   offs_g    = (int*)(ws);            // 17 ints
    int*   n_gu      = (int*)(ws + 128);
    int*   n_dn      = (int*)(ws + 132);
    int*   wl_gu     = (int*)(ws + 1024);     // up to 3072 ints
    int*   wl_dn     = (int*)(ws + 16384);    // up to 2048 ints
    int*   tok_e     = (int*)(ws + 32768);
    float* tok_w     = (float*)(ws + 40960);
    int*   row_token = (int*)(ws + 49152);
    float* row_w     = (float*)(ws + 57344);
    bf16*  xb        = (bf16*)(ws + 65536);
    bf16*  act       = (bf16*)(ws + 65536 + (1 << 21));
    bf16*  act2      = (bf16*)(ws + 65536 + (2 << 21));

    hipMemsetAsync(out, 0, (size_t)T_TOK * H_DIM * sizeof(float), stream);
    k_cast_router<<<T_TOK / 4, 256, 0, stream>>>(x, gw, bias, xb, tok_e, tok_w);
    k_build<<<1, 256, 0, stream>>>(tok_e, tok_w, offs_g, row_token, row_w,
                                   wl_gu, n_gu, wl_dn, n_dn);
    k_gu_all<<<GU_GRID, 256, 0, stream>>>(xb, wgu, sgu, act, act2,
                                          offs_g, row_token, wl_gu, n_gu);
    k_dn_all<<<DN_GRID, 256, 0, stream>>>(act, act2, wd, sd, out,
                                          offs_g, row_token, row_w, wl_dn, n_dn);
}

// Round 8
// 92.387 us; speedup vs baseline: 2.0897x; 1.2464x over previous
//
#include <hip/hip_runtime.h>
#include <math.h>

#define T_TOK 1024
#define H_DIM 1024
#define NEXP  16
#define I_DIM 512
#define ISH   1024
#define GU_GRID 384
#define DN_GRID 768

typedef __bf16 bf16;
typedef __bf16 bf16x4 __attribute__((ext_vector_type(4)));
typedef __bf16 bf16x8 __attribute__((ext_vector_type(8)));
typedef float  f32x4  __attribute__((ext_vector_type(4)));

#define MFMA(a,b,c) __builtin_amdgcn_mfma_f32_16x16x32_bf16(a,b,c,0,0,0)

__device__ __forceinline__ bf16x8 cvt8(float4 a, float4 b) {
    return (bf16x8){ (bf16)a.x,(bf16)a.y,(bf16)a.z,(bf16)a.w,
                     (bf16)b.x,(bf16)b.y,(bf16)b.z,(bf16)b.w };
}

// ---------------- fused cast(x->bf16) + router ----------------
__global__ __launch_bounds__(256) void k_cast_router(const float* __restrict__ x,
        const float* __restrict__ gw, const float* __restrict__ bias,
        bf16* __restrict__ xb, int* __restrict__ tok_e, float* __restrict__ tok_w)
{
    int t = blockIdx.x * 4 + (threadIdx.x >> 6);
    int lane = threadIdx.x & 63;
    const float* xrow = x + (size_t)t * H_DIM + lane * 16;
    bf16* xbrow = xb + (size_t)t * H_DIM + lane * 16;
    float acc[NEXP];
    #pragma unroll
    for (int e = 0; e < NEXP; ++e) acc[e] = 0.f;
    #pragma unroll
    for (int kc = 0; kc < 4; ++kc) {
        float4 xv = *(const float4*)(xrow + kc * 4);
        bf16x4 o = { (bf16)xv.x, (bf16)xv.y, (bf16)xv.z, (bf16)xv.w };
        *(bf16x4*)(xbrow + kc * 4) = o;
        const float* gp = gw + lane * 16 + kc * 4;
        #pragma unroll
        for (int e = 0; e < NEXP; ++e) {
            float4 wv = *(const float4*)(gp + e * H_DIM);
            acc[e] += xv.x * wv.x + xv.y * wv.y + xv.z * wv.z + xv.w * wv.w;
        }
    }
    #pragma unroll
    for (int e = 0; e < NEXP; ++e) {
        float v = acc[e];
        #pragma unroll
        for (int off = 1; off < 64; off <<= 1) v += __shfl_xor(v, off);
        acc[e] = v;
    }
    if (lane == 0) {
        float sc[NEXP], bi[NEXP];
        #pragma unroll
        for (int e = 0; e < NEXP; ++e) {
            sc[e] = 1.f / (1.f + expf(-acc[e]));
            bi[e] = sc[e] + bias[e];
        }
        int i1 = 0; float b1 = bi[0];
        for (int e = 1; e < NEXP; ++e) if (bi[e] > b1) { b1 = bi[e]; i1 = e; }
        int i2 = -1; float b2 = -1e30f;
        for (int e = 0; e < NEXP; ++e) { if (e == i1) continue; if (bi[e] > b2) { b2 = bi[e]; i2 = e; } }
        float w1 = sc[i1], w2 = sc[i2];
        float s = w1 + w2;
        w1 /= s; w2 /= s;
        tok_e[t * 2]     = i1;  tok_e[t * 2 + 1] = i2;
        tok_w[t * 2]     = w1;  tok_w[t * 2 + 1] = w2;
    }
}

// ---------------- build: histogram + scan + scatter + BM=128 worklists ----------------
// entry: (ge<<20)|(kh<<18)|(mt<<12)|nx ; ge==16 => shared
__global__ __launch_bounds__(256) void k_build(const int* __restrict__ tok_e,
        const float* __restrict__ tok_w, int* __restrict__ offs_g,
        int* __restrict__ row_token, float* __restrict__ row_w,
        int* __restrict__ wl_gu, int* __restrict__ n_gu,
        int* __restrict__ wl_dn, int* __restrict__ n_dn)
{
    __shared__ int cnt[NEXP], cur[NEXP], tcnt[NEXP], toff[NEXP + 1];
    int tid = threadIdx.x;
    if (tid < NEXP) cnt[tid] = 0;
    __syncthreads();
    for (int p = tid; p < 2 * T_TOK; p += 256) atomicAdd(&cnt[tok_e[p]], 1);
    __syncthreads();
    if (tid == 0) {
        int s = 0, ts = 0;
        for (int e = 0; e < NEXP; ++e) {
            offs_g[e] = s; cur[e] = s;
            tcnt[e] = (cnt[e] + 127) >> 7;          // BM=128 tiles
            toff[e] = ts; ts += tcnt[e]; s += cnt[e];
        }
        offs_g[NEXP] = s; toff[NEXP] = ts;
        *n_gu = ts * 8 + 128;     // routed: 8 nx ; shared: 8 mt * 16 nx
        *n_dn = ts * 16 + 256;    // routed: 16 nx ; shared: 8 mt * 16 nx * 2 kh
    }
    __syncthreads();
    for (int p = tid; p < 2 * T_TOK; p += 256) {
        int e = tok_e[p];
        int pos = atomicAdd(&cur[e], 1);
        row_token[pos] = p >> 1;
        row_w[pos] = tok_w[p];
    }
    int ntr = toff[NEXP];
    int tot_gu = ntr * 8 + 128;
    for (int idx = tid; idx < tot_gu; idx += 256) {
        int entry;
        if (idx < ntr * 8) {
            int t8 = idx >> 3;
            int e = 0;
            while (!(t8 >= toff[e] && t8 < toff[e + 1])) ++e;
            int j = idx - toff[e] * 8;
            int nx = j / tcnt[e], mt = j % tcnt[e];   // nx outer, mt inner
            entry = (e << 20) | (mt << 12) | nx;
        } else {
            int j = idx - ntr * 8;
            int nx = j >> 3, mt = j & 7;
            entry = (16 << 20) | (mt << 12) | nx;
        }
        wl_gu[idx] = entry;
    }
    int tot_dn = ntr * 16 + 256;
    for (int idx = tid; idx < tot_dn; idx += 256) {
        int entry;
        if (idx < ntr * 16) {
            int t16 = idx >> 4;
            int e = 0;
            while (!(t16 >= toff[e] && t16 < toff[e + 1])) ++e;
            int j = idx - toff[e] * 16;
            int nx = j / tcnt[e], mt = j % tcnt[e];
            entry = (e << 20) | (mt << 12) | nx;
        } else {
            int j = idx - ntr * 16;
            int nx = j >> 4, r = j & 15;
            int mt = r >> 1, kh = r & 1;
            entry = (16 << 20) | (kh << 18) | (mt << 12) | nx;
        }
        wl_dn[idx] = entry;
    }
}

// ---------------- gate_up + SwiGLU: BM=128, BN=64g+64u, BK=64 ----------------
__global__ __launch_bounds__(256) void k_gu(
    const bf16* __restrict__ xb, const float* __restrict__ wgu, const float* __restrict__ sgu,
    bf16* __restrict__ act, bf16* __restrict__ act2,
    const int* __restrict__ offs, const int* __restrict__ row_token,
    const int* __restrict__ wl, const int* __restrict__ n_wl)
{
    int bid = blockIdx.x;
    int idx = (bid & 7) * (GU_GRID >> 3) + (bid >> 3);
    if (idx >= *n_wl) return;
    int entry = wl[idx];
    int ge = entry >> 20;
    bool sh = (ge == 16);
    int mt = (entry >> 12) & 63, nx = entry & 255;
    int n0 = nx * 64;
    int m0, mcnt, ldo;
    const float *Wg, *Wu;
    bf16* dst;
    if (sh) {
        m0 = mt * 128; mcnt = 128; ldo = ISH; dst = act2;
        Wg = sgu + (size_t)(n0) * H_DIM;
        Wu = sgu + (size_t)(ISH + n0) * H_DIM;
    } else {
        m0 = offs[ge] + mt * 128; mcnt = min(128, offs[ge + 1] - m0);
        ldo = I_DIM; dst = act;
        const float* W = wgu + (size_t)ge * (2 * (size_t)I_DIM * H_DIM);
        Wg = W + (size_t)(n0) * H_DIM;
        Wu = W + (size_t)(I_DIM + n0) * H_DIM;
    }

    __shared__ bf16 As[128][72];
    __shared__ bf16 Bg[64][72];
    __shared__ bf16 Bu[64][72];
    __shared__ int  toks[128];

    int tid = threadIdx.x;
    if (tid < 128) toks[tid] = sh ? (m0 + tid) : row_token[m0 + min(tid, mcnt - 1)];
    __syncthreads();

    // A staging: 4 chunks/thread; chunk = c*256+tid -> row = c*32 + tid>>3, col8 = (tid&7)*8
    int arsub = tid >> 3, ac8 = (tid & 7) * 8;
    const bf16* pa[4];
    #pragma unroll
    for (int c = 0; c < 4; ++c)
        pa[c] = xb + (size_t)toks[c * 32 + arsub] * H_DIM + ac8;
    // B staging: row = tid>>2, 16 consecutive f32 at col (tid&3)*16
    int brow = tid >> 2, bc = (tid & 3) * 16;
    const float* pg = Wg + (size_t)brow * H_DIM + bc;
    const float* pu = Wu + (size_t)brow * H_DIM + bc;

    int lane = tid & 63, w = tid >> 6, wm = w >> 1, wn = w & 1;
    int lr = lane & 15, hi = lane >> 4, lk8 = hi * 8;

    f32x4 aG[4][2], aU[4][2];
    #pragma unroll
    for (int m = 0; m < 4; ++m)
        #pragma unroll
        for (int n = 0; n < 2; ++n) { aG[m][n] = (f32x4){0,0,0,0}; aU[m][n] = (f32x4){0,0,0,0}; }

    for (int k0 = 0; k0 < H_DIM; k0 += 64) {
        bf16x8 a8[4];
        #pragma unroll
        for (int c = 0; c < 4; ++c) a8[c] = *(const bf16x8*)(pa[c] + k0);
        float4 g0 = *(const float4*)(pg + k0),     g1 = *(const float4*)(pg + k0 + 4);
        float4 g2 = *(const float4*)(pg + k0 + 8), g3 = *(const float4*)(pg + k0 + 12);
        float4 u0 = *(const float4*)(pu + k0),     u1 = *(const float4*)(pu + k0 + 4);
        float4 u2 = *(const float4*)(pu + k0 + 8), u3 = *(const float4*)(pu + k0 + 12);
        #pragma unroll
        for (int c = 0; c < 4; ++c) *(bf16x8*)&As[c * 32 + arsub][ac8] = a8[c];
        *(bf16x8*)&Bg[brow][bc]     = cvt8(g0, g1);
        *(bf16x8*)&Bg[brow][bc + 8] = cvt8(g2, g3);
        *(bf16x8*)&Bu[brow][bc]     = cvt8(u0, u1);
        *(bf16x8*)&Bu[brow][bc + 8] = cvt8(u2, u3);
        __syncthreads();
        #pragma unroll
        for (int ks = 0; ks < 2; ++ks) {
            bf16x8 fa[4], fg[2], fu[2];
            #pragma unroll
            for (int m = 0; m < 4; ++m)
                fa[m] = *(const bf16x8*)&As[wm * 64 + m * 16 + lr][ks * 32 + lk8];
            #pragma unroll
            for (int n = 0; n < 2; ++n) {
                fg[n] = *(const bf16x8*)&Bg[wn * 32 + n * 16 + lr][ks * 32 + lk8];
                fu[n] = *(const bf16x8*)&Bu[wn * 32 + n * 16 + lr][ks * 32 + lk8];
            }
            #pragma unroll
            for (int m = 0; m < 4; ++m)
                #pragma unroll
                for (int n = 0; n < 2; ++n) {
                    aG[m][n] = MFMA(fa[m], fg[n], aG[m][n]);
                    aU[m][n] = MFMA(fa[m], fu[n], aU[m][n]);
                }
        }
        __syncthreads();
    }

    #pragma unroll
    for (int m = 0; m < 4; ++m) {
        #pragma unroll
        for (int j = 0; j < 4; ++j) {
            int rl = wm * 64 + m * 16 + hi * 4 + j;
            if (rl < mcnt) {
                #pragma unroll
                for (int n = 0; n < 2; ++n) {
                    float g = aG[m][n][j], u = aU[m][n][j];
                    float v = (g / (1.f + __expf(-g))) * u;
                    dst[(size_t)(m0 + rl) * ldo + n0 + wn * 32 + n * 16 + lr] = (bf16)v;
                }
            }
        }
    }
}

// ---------------- down proj: BM=128, BN=64, BK=64, K=512 (shared split-K) ----------------
__global__ __launch_bounds__(256) void k_dn(
    const bf16* __restrict__ act, const bf16* __restrict__ act2,
    const float* __restrict__ wd, const float* __restrict__ sd, float* __restrict__ out,
    const int* __restrict__ offs, const int* __restrict__ row_token, const float* __restrict__ row_w,
    const int* __restrict__ wl, const int* __restrict__ n_wl)
{
    int bid = blockIdx.x;
    int idx = (bid & 7) * (DN_GRID >> 3) + (bid >> 3);
    if (idx >= *n_wl) return;
    int entry = wl[idx];
    int ge = entry >> 20;
    bool sh = (ge == 16);
    int kh = (entry >> 18) & 3;
    int mt = (entry >> 12) & 63, nx = entry & 255;
    int n0 = nx * 64;
    int m0, mcnt, lda, ldw, kb;
    const bf16* A;
    const float* W;
    if (sh) {
        m0 = mt * 128; mcnt = 128; A = act2; lda = ISH; W = sd; ldw = ISH; kb = kh * 512;
    } else {
        m0 = offs[ge] + mt * 128; mcnt = min(128, offs[ge + 1] - m0);
        A = act; lda = I_DIM; W = wd + (size_t)ge * H_DIM * I_DIM; ldw = I_DIM; kb = 0;
    }

    __shared__ bf16 As[128][72];
    __shared__ bf16 Bs[64][72];

    int tid = threadIdx.x;
    int arsub = tid >> 3, ac8 = (tid & 7) * 8;
    const bf16* pa[4];
    #pragma unroll
    for (int c = 0; c < 4; ++c) {
        int r = min(c * 32 + arsub, mcnt - 1);
        pa[c] = A + (size_t)(m0 + r) * lda + kb + ac8;
    }
    int brow = tid >> 2, bc = (tid & 3) * 16;
    const float* pb = W + (size_t)(n0 + brow) * ldw + kb + bc;

    int lane = tid & 63, w = tid >> 6, wm = w >> 1, wn = w & 1;
    int lr = lane & 15, hi = lane >> 4, lk8 = hi * 8;

    f32x4 acc[4][2];
    #pragma unroll
    for (int m = 0; m < 4; ++m)
        #pragma unroll
        for (int n = 0; n < 2; ++n) acc[m][n] = (f32x4){0,0,0,0};

    for (int k0 = 0; k0 < 512; k0 += 64) {
        bf16x8 a8[4];
        #pragma unroll
        for (int c = 0; c < 4; ++c) a8[c] = *(const bf16x8*)(pa[c] + k0);
        float4 b0 = *(const float4*)(pb + k0),     b1 = *(const float4*)(pb + k0 + 4);
        float4 b2 = *(const float4*)(pb + k0 + 8), b3 = *(const float4*)(pb + k0 + 12);
        #pragma unroll
        for (int c = 0; c < 4; ++c) *(bf16x8*)&As[c * 32 + arsub][ac8] = a8[c];
        *(bf16x8*)&Bs[brow][bc]     = cvt8(b0, b1);
        *(bf16x8*)&Bs[brow][bc + 8] = cvt8(b2, b3);
        __syncthreads();
        #pragma unroll
        for (int ks = 0; ks < 2; ++ks) {
            bf16x8 fa[4], fb[2];
            #pragma unroll
            for (int m = 0; m < 4; ++m)
                fa[m] = *(const bf16x8*)&As[wm * 64 + m * 16 + lr][ks * 32 + lk8];
            #pragma unroll
            for (int n = 0; n < 2; ++n)
                fb[n] = *(const bf16x8*)&Bs[wn * 32 + n * 16 + lr][ks * 32 + lk8];
            #pragma unroll
            for (int m = 0; m < 4; ++m)
                #pragma unroll
                for (int n = 0; n < 2; ++n)
                    acc[m][n] = MFMA(fa[m], fb[n], acc[m][n]);
        }
        __syncthreads();
    }

    #pragma unroll
    for (int m = 0; m < 4; ++m) {
        #pragma unroll
        for (int j = 0; j < 4; ++j) {
            int rl = wm * 64 + m * 16 + hi * 4 + j;
            if (rl < mcnt) {
                if (sh) {
                    #pragma unroll
                    for (int n = 0; n < 2; ++n)
                        atomicAdd(&out[(size_t)(m0 + rl) * H_DIM + n0 + wn * 32 + n * 16 + lr],
                                  acc[m][n][j]);
                } else {
                    int t = row_token[m0 + rl];
                    float wt = row_w[m0 + rl];
                    #pragma unroll
                    for (int n = 0; n < 2; ++n)
                        atomicAdd(&out[(size_t)t * H_DIM + n0 + wn * 32 + n * 16 + lr],
                                  wt * acc[m][n][j]);
                }
            }
        }
    }
}

extern "C" void kernel_launch(void* const* d_in, const int* in_sizes, int n_in,
                              void* d_out, int out_size, void* d_ws, size_t ws_size,
                              hipStream_t stream)
{
    (void)in_sizes; (void)n_in; (void)out_size; (void)ws_size;
    const float* x    = (const float*)d_in[0];
    const float* gw   = (const float*)d_in[1];
    const float* bias = (const float*)d_in[2];
    const float* wgu  = (const float*)d_in[3];
    const float* wd   = (const float*)d_in[4];
    const float* sgu  = (const float*)d_in[5];
    const float* sd   = (const float*)d_in[6];
    float* out = (float*)d_out;

    char* ws = (char*)d_ws;
    int*   offs_g    = (int*)(ws);
    int*   n_gu      = (int*)(ws + 128);
    int*   n_dn      = (int*)(ws + 132);
    int*   wl_gu     = (int*)(ws + 1024);
    int*   wl_dn     = (int*)(ws + 16384);
    int*   tok_e     = (int*)(ws + 32768);
    float* tok_w     = (float*)(ws + 40960);
    int*   row_token = (int*)(ws + 49152);
    float* row_w     = (float*)(ws + 57344);
    bf16*  xb        = (bf16*)(ws + 65536);
    bf16*  act       = (bf16*)(ws + 65536 + (1 << 21));
    bf16*  act2      = (bf16*)(ws + 65536 + (2 << 21));

    hipMemsetAsync(out, 0, (size_t)T_TOK * H_DIM * sizeof(float), stream);
    k_cast_router<<<T_TOK / 4, 256, 0, stream>>>(x, gw, bias, xb, tok_e, tok_w);
    k_build<<<1, 256, 0, stream>>>(tok_e, tok_w, offs_g, row_token, row_w,
                                   wl_gu, n_gu, wl_dn, n_dn);
    k_gu<<<GU_GRID, 256, 0, stream>>>(xb, wgu, sgu, act, act2,
                                      offs_g, row_token, wl_gu, n_gu);
    k_dn<<<DN_GRID, 256, 0, stream>>>(act, act2, wd, sd, out,
                                      offs_g, row_token, row_w, wl_dn, n_dn);
}